// Round 3
// baseline (5681.215 us; speedup 1.0000x reference)
//
#include <hip/hip_runtime.h>

#define T_STEPS 365
#define NCELLS  65536

typedef __attribute__((ext_vector_type(8))) short short8;   // 8 bf16 = 4 VGPRs
typedef __attribute__((ext_vector_type(4))) float f32x4;
typedef __attribute__((ext_vector_type(4))) unsigned int u32x4;

static __device__ __forceinline__ short f2bf_rne(float x) {
    union { float f; unsigned u; } v; v.f = x;
    unsigned r = v.u + 0x7fffu + ((v.u >> 16) & 1u);   // round-nearest-even
    return (short)(r >> 16);
}
static __device__ __forceinline__ float bf2f(short b) {
    union { float f; unsigned u; } v; v.u = ((unsigned)(unsigned short)b) << 16;
    return v.f;
}
static __device__ __forceinline__ unsigned pack2(short lo, short hi) {
    return ((unsigned)(unsigned short)lo) | (((unsigned)(unsigned short)hi) << 16);
}
static __device__ __forceinline__ float fast_rcp(float x) { return __builtin_amdgcn_rcpf(x); }

// One wave = 16 cells, all 365 steps. h@W_hh^T on MFMA (split-h bf16 hi+lo).
// R3: W_hh B-frags live in LDS ([frag][lane] 16B contiguous = conflict-free),
// freeing ~96 regs -> 3 waves/SIMD. r/z igates + bias folded into MFMA via an
// extra K-chunk (A-ext = [p,t,1,1,p_lo,t_lo,0,0]); q!=0 lanes read a zero
// region (same-address broadcast, free). n-gate x-part stays on VALU because
// bias_n sits inside the reset product.
__global__ __launch_bounds__(256, 3)
void gru_mfma_kernel(const float* __restrict__ precip,
                     const float* __restrict__ temp,
                     const float* __restrict__ w_ih,    // (192,2)
                     const float* __restrict__ w_hh,    // (192,64)
                     const float* __restrict__ bias,    // (192)
                     const float* __restrict__ bias_n,  // (64)
                     const float* __restrict__ out_w,   // (64)
                     const float* __restrict__ out_b,   // (1)
                     const float* __restrict__ init_h,  // (64)
                     float* __restrict__ out)
{
    __shared__ u32x4 Bfrag[1536];        // 24 KiB: w_hh frags [ (jt*2+f)*64 + lane ]
    __shared__ u32x4 BExt[256];          // 4 KiB: [0..127] ext frags (jt*16+c), [128..255] zeros
    __shared__ float hbuf[4][16][68];    // 17 KiB: [wave][cell][unit], stride 68 = aligned + 2-way

    const int tid  = threadIdx.x;
    const int lane = tid & 63;
    const int wid  = tid >> 6;
    const int c    = lane & 15;
    const int q    = lane >> 4;
    const int base = (blockIdx.x * 4 + wid) * 16;

    // ---- build LDS B fragments (one-time) ----
    for (int idx = tid; idx < 1536; idx += 256) {
        const int l = idx & 63, jtf = idx >> 6;
        const int jt = jtf >> 1, f = jtf & 1;
        const float* src = w_hh + ((16 * jt + (l & 15)) * 64 + 32 * f + 8 * (l >> 4));
        u32x4 d;
#pragma unroll
        for (int p2 = 0; p2 < 4; ++p2)
            d[p2] = pack2(f2bf_rne(src[2 * p2]), f2bf_rne(src[2 * p2 + 1]));
        Bfrag[idx] = d;
    }
    if (tid < 128) {
        const int jt = tid >> 4, cc = tid & 15;
        const int g = 16 * jt + cc;                 // gate rows 0..127 (r then z)
        const float b = bias[g];
        const short bh = f2bf_rne(b);
        const short bl = f2bf_rne(b - bf2f(bh));
        u32x4 d;
        d[0] = pack2(f2bf_rne(w_ih[2 * g]), f2bf_rne(w_ih[2 * g + 1]));
        d[1] = pack2(bh, bl);                      // x (1,1) in A-ext -> exact fp32 bias
        d[2] = d[0];                               // multiplies (p_lo, t_lo)
        d[3] = 0u;
        BExt[tid] = d;
        BExt[128 + tid] = u32x4{0u, 0u, 0u, 0u};   // zero region: 2 KiB, imm-offset reachable
    }

    // ---- per-lane constants: n-gate x-part + out_w (unit u = 16j + c)
    float wn0[4], wn1[4], bn_[4], bnn[4], ow[4];
#pragma unroll
    for (int j = 0; j < 4; ++j) {
        const int u = 16 * j + c;
        wn0[j] = w_ih[256 + 2 * u]; wn1[j] = w_ih[257 + 2 * u];
        bn_[j] = bias[128 + u]; bnn[j] = bias_n[u]; ow[j] = out_w[u];
    }
    const float ob = out_b[0];

    // ---- h state (C-layout) + prime LDS A-layout buffer
    float hC[4][4];
#pragma unroll
    for (int j = 0; j < 4; ++j) {
        const float iv = init_h[16 * j + c];
#pragma unroll
        for (int reg = 0; reg < 4; ++reg) hC[j][reg] = iv;
    }
#pragma unroll
    for (int j = 0; j < 4; ++j)
#pragma unroll
        for (int reg = 0; reg < 4; ++reg)
            hbuf[wid][4 * q + reg][16 * j + c] = hC[j][reg];

    __syncthreads();

    // per-lane ext-B pointer: q==0 lanes -> real frags (+ jt*256B imm), others -> zero region
    const u32x4* extp = BExt + ((q == 0) ? c : 128);
    const u32x4* bfl  = Bfrag + lane;
    const unsigned amask = (q == 0) ? 0xFFFFFFFFu : 0u;

    const bool selb0 = (c & 1), selb1 = (c & 2);
    const bool do_store = (c < 4);

#pragma unroll 1
    for (int t = 0; t < T_STEPS; ++t) {
        const size_t tofs = (size_t)t * NCELLS + base;
        float pv[4], tv[4];
#pragma unroll
        for (int reg = 0; reg < 4; ++reg) {
            pv[reg] = precip[tofs + 4 * q + reg];
            tv[reg] = temp  [tofs + 4 * q + reg];
        }
        const float pc = precip[tofs + c];
        const float tc = temp  [tofs + c];

        // ---- A-frags from LDS, split hi/lo bf16
        const float* row = &hbuf[wid][c][0];
        f32x4 a0 = *(const f32x4*)(row + 8 * q);
        f32x4 a1 = *(const f32x4*)(row + 8 * q + 4);
        f32x4 a2 = *(const f32x4*)(row + 32 + 8 * q);
        f32x4 a3 = *(const f32x4*)(row + 32 + 8 * q + 4);
        short8 ah0, al0, ah1, al1;
#pragma unroll
        for (int e = 0; e < 4; ++e) {
            short h0 = f2bf_rne(a0[e]); ah0[e]     = h0; al0[e]     = f2bf_rne(a0[e] - bf2f(h0));
            short h1 = f2bf_rne(a1[e]); ah0[4 + e] = h1; al0[4 + e] = f2bf_rne(a1[e] - bf2f(h1));
            short h2 = f2bf_rne(a2[e]); ah1[e]     = h2; al1[e]     = f2bf_rne(a2[e] - bf2f(h2));
            short h3 = f2bf_rne(a3[e]); ah1[4 + e] = h3; al1[4 + e] = f2bf_rne(a3[e] - bf2f(h3));
        }

        // ---- A-ext chunk: [p_hi, t_hi, 1, 1, p_lo, t_lo, 0, 0] on q==0 lanes only
        const short pch = f2bf_rne(pc), tch = f2bf_rne(tc);
        const short pcl = f2bf_rne(pc - bf2f(pch)), tcl = f2bf_rne(tc - bf2f(tch));
        union { u32x4 u; short8 s; } aeu;
        aeu.u[0] = pack2(pch, tch) & amask;
        aeu.u[1] = 0x3F803F80u & amask;            // (1.0bf, 1.0bf)
        aeu.u[2] = pack2(pcl, tcl) & amask;
        aeu.u[3] = 0u;
        const short8 aext = aeu.s;

        // ---- hgates: r/z tiles get the ext chunk (x + bias); n tiles h-only
        f32x4 acc[12];
        const f32x4 zero4 = {0.f, 0.f, 0.f, 0.f};
#pragma unroll
        for (int jt = 0; jt < 12; ++jt) {
            union { u32x4 u; short8 s; } b0, b1;
            b0.u = bfl[2 * jt * 64];
            b1.u = bfl[(2 * jt + 1) * 64];
            f32x4 a;
            if (jt < 8) {
                union { u32x4 u; short8 s; } be; be.u = extp[jt * 16];
                a = __builtin_amdgcn_mfma_f32_16x16x32_bf16(aext, be.s, zero4, 0, 0, 0);
            } else {
                a = zero4;
            }
            a = __builtin_amdgcn_mfma_f32_16x16x32_bf16(ah0, b0.s, a, 0, 0, 0);
            a = __builtin_amdgcn_mfma_f32_16x16x32_bf16(ah1, b1.s, a, 0, 0, 0);
            a = __builtin_amdgcn_mfma_f32_16x16x32_bf16(al0, b0.s, a, 0, 0, 0);
            a = __builtin_amdgcn_mfma_f32_16x16x32_bf16(al1, b1.s, a, 0, 0, 0);
            acc[jt] = a;
        }

        // ---- elementwise GRU update in C-layout
        float psum[4] = {0.f, 0.f, 0.f, 0.f};
#pragma unroll
        for (int j = 0; j < 4; ++j) {
#pragma unroll
            for (int reg = 0; reg < 4; ++reg) {
                const float xr = acc[j][reg];          // ir + hr + bias_r (complete)
                const float xz = acc[4 + j][reg];      // iz + hz + bias_z (complete)
                const float hn = acc[8 + j][reg];      // h-part only
                const float in_ = fmaf(wn0[j], pv[reg], fmaf(wn1[j], tv[reg], bn_[j]));
                const float r  = fast_rcp(1.f + __expf(-xr));
                const float z  = fast_rcp(1.f + __expf(-xz));
                const float a_ = fmaf(r, hn + bnn[j], in_);
                const float th = fmaf(-2.f, fast_rcp(1.f + __expf(a_ + a_)), 1.f);
                const float hnew = fmaf(z, hC[j][reg] - th, th);
                hC[j][reg] = hnew;
                psum[reg] = fmaf(hnew, ow[j], psum[reg]);
            }
        }

        // ---- write h' back in A-layout (wave-private, no barrier)
#pragma unroll
        for (int j = 0; j < 4; ++j)
#pragma unroll
            for (int reg = 0; reg < 4; ++reg)
                hbuf[wid][4 * q + reg][16 * j + c] = hC[j][reg];

        // ---- y = h' @ out_w + ob : butterfly within each 16-lane group
#pragma unroll
        for (int reg = 0; reg < 4; ++reg) {
            psum[reg] += __shfl_xor(psum[reg], 1);
            psum[reg] += __shfl_xor(psum[reg], 2);
            psum[reg] += __shfl_xor(psum[reg], 4);
            psum[reg] += __shfl_xor(psum[reg], 8);
        }
        float ya = selb0 ? psum[1] : psum[0];
        float yb = selb0 ? psum[3] : psum[2];
        float yv = selb1 ? yb : ya;
        if (do_store) out[tofs + 4 * q + c] = yv + ob;
    }

    // ---- final_h: out[T*N + cell*64 + u]
    const size_t fofs = (size_t)T_STEPS * NCELLS + (size_t)base * 64;
#pragma unroll
    for (int j = 0; j < 4; ++j)
#pragma unroll
        for (int reg = 0; reg < 4; ++reg)
            out[fofs + (size_t)(4 * q + reg) * 64 + 16 * j + c] = hC[j][reg];
}

extern "C" void kernel_launch(void* const* d_in, const int* in_sizes, int n_in,
                              void* d_out, int out_size, void* d_ws, size_t ws_size,
                              hipStream_t stream) {
    const float* precip = (const float*)d_in[0];
    const float* temp   = (const float*)d_in[1];
    const float* w_ih   = (const float*)d_in[2];
    const float* w_hh   = (const float*)d_in[3];
    const float* bias   = (const float*)d_in[4];
    const float* bias_n = (const float*)d_in[5];
    const float* out_w  = (const float*)d_in[6];
    const float* out_b  = (const float*)d_in[7];
    const float* init_h = (const float*)d_in[8];

    gru_mfma_kernel<<<NCELLS / 64, 256, 0, stream>>>(
        precip, temp, w_ih, w_hh, bias, bias_n, out_w, out_b, init_h,
        (float*)d_out);
}